// Round 1
// baseline (3478.729 us; speedup 1.0000x reference)
//
#include <hip/hip_runtime.h>
#include <cmath>

#define NODES 40000
#define EDGES 600000
#define HD    128
#define BN_EPS 1e-5f

// agg[i] = x[i]  (self term of GIN, eps=0)
__global__ __launch_bounds__(256) void init_copy(const float4* __restrict__ src,
                                                 float4* __restrict__ dst, int n4) {
  int i = blockIdx.x * 256 + threadIdx.x;
  if (i < n4) dst[i] = src[i];
}

// agg[dst[e]] += x[src[e]]  — edge-parallel, 1 thread per (edge, float4 chunk)
__global__ __launch_bounds__(256) void edge_scatter(const float* __restrict__ x,
                                                    const int* __restrict__ ei,
                                                    float* __restrict__ agg) {
  int idx = blockIdx.x * 256 + threadIdx.x;
  int e = idx >> 5;          // HD/4 = 32 chunks per edge
  int c = idx & 31;
  if (e >= EDGES) return;
  int s = ei[e];
  int d = ei[EDGES + e];
  float4 v = ((const float4*)(x + (size_t)s * HD))[c];
  float* p = agg + (size_t)d * HD + c * 4;
  atomicAdd(p + 0, v.x);
  atomicAdd(p + 1, v.y);
  atomicAdd(p + 2, v.z);
  atomicAdd(p + 3, v.w);
}

// out[M x NC] = epilogue(A[M x 128] @ W[128 x NC] + bias)
// EPI: 1 = BatchNorm+ELU, 2 = ELU, 3 = none
// Block 256 threads, tile 128 rows x NC cols, per-thread 8 x (NC/16).
template <int NC, int EPI>
__global__ __launch_bounds__(256) void gemm_fused(
    const float* __restrict__ A, const float* __restrict__ W,
    const float* __restrict__ bias, const float* __restrict__ g,
    const float* __restrict__ bt, const float* __restrict__ mu,
    const float* __restrict__ var, float* __restrict__ out) {
  constexpr int BM = 128, BK = 32, TM = 8, TN = NC / 16;
  __shared__ float Ast[BK][BM + 4];   // A tile, transposed: Ast[k][m] (+4 pad keeps 16B row align)
  __shared__ float Ws[BK][NC + 4];

  const int tid = threadIdx.x;
  const int tx = tid & 15;   // column group
  const int ty = tid >> 4;   // row group
  const int m0 = blockIdx.x * BM;

  float acc[TM][TN];
#pragma unroll
  for (int i = 0; i < TM; ++i)
#pragma unroll
    for (int j = 0; j < TN; ++j) acc[i][j] = 0.f;

  for (int k0 = 0; k0 < HD; k0 += BK) {
    // Stage A tile (BM x BK), transposed into LDS. 1024 float4 loads / 256 thr.
#pragma unroll
    for (int it = 0; it < 4; ++it) {
      int t = tid + it * 256;        // 0..1023
      int r = t >> 3;                // tile row (8 float4 per row)
      int cc = t & 7;
      int m = m0 + r;
      float4 v = make_float4(0.f, 0.f, 0.f, 0.f);
      if (m < NODES) v = *(const float4*)(A + (size_t)m * HD + k0 + cc * 4);
      Ast[cc * 4 + 0][r] = v.x;
      Ast[cc * 4 + 1][r] = v.y;
      Ast[cc * 4 + 2][r] = v.z;
      Ast[cc * 4 + 3][r] = v.w;
    }
    // Stage W tile (BK x NC)
    constexpr int F4 = NC / 4;
#pragma unroll
    for (int t = tid; t < BK * F4; t += 256) {
      int r = t / F4;
      int cc = t % F4;
      *(float4*)&Ws[r][cc * 4] = *(const float4*)(W + (size_t)(k0 + r) * NC + cc * 4);
    }
    __syncthreads();

#pragma unroll
    for (int k = 0; k < BK; ++k) {
      float a[TM], w[TN];
      *(float4*)&a[0] = *(const float4*)&Ast[k][ty * TM + 0];
      *(float4*)&a[4] = *(const float4*)&Ast[k][ty * TM + 4];
#pragma unroll
      for (int j4 = 0; j4 < TN; j4 += 4)
        *(float4*)&w[j4] = *(const float4*)&Ws[k][tx * TN + j4];
#pragma unroll
      for (int i = 0; i < TM; ++i)
#pragma unroll
        for (int j = 0; j < TN; ++j)
          acc[i][j] = fmaf(a[i], w[j], acc[i][j]);
    }
    __syncthreads();
  }

  // Epilogue + store
#pragma unroll
  for (int i = 0; i < TM; ++i) {
    int m = m0 + ty * TM + i;
    if (m >= NODES) break;
#pragma unroll
    for (int j = 0; j < TN; ++j) {
      int c = tx * TN + j;
      float t = acc[i][j] + bias[c];
      if (EPI == 1) {
        float rs = rsqrtf(var[c] + BN_EPS);
        t = (t - mu[c]) * rs * g[c] + bt[c];
      }
      if (EPI <= 2) t = t > 0.f ? t : expm1f(t);   // ELU, alpha=1
      acc[i][j] = t;
    }
#pragma unroll
    for (int j4 = 0; j4 < TN; j4 += 4)
      *(float4*)(out + (size_t)m * NC + tx * TN + j4) = *(float4*)&acc[i][j4];
  }
}

extern "C" void kernel_launch(void* const* d_in, const int* in_sizes, int n_in,
                              void* d_out, int out_size, void* d_ws, size_t ws_size,
                              hipStream_t stream) {
  const float* x = (const float*)d_in[0];
  const int* ei  = (const int*)d_in[1];
  const float* p[30];
  for (int i = 0; i < 30 && i < n_in; ++i) p[i] = (const float*)d_in[i];

  float* b0 = (float*)d_ws;                       // agg buffer
  float* b1 = b0 + (size_t)NODES * HD;            // h after MLP layer 1
  float* b2 = b1 + (size_t)NODES * HD;            // h after conv (layer output)

  const int n4 = NODES * HD / 4;
  dim3 blk(256);
  const int initGrid = (n4 + 255) / 256;                 // 5000
  const int scatGrid = (EDGES * 32 + 255) / 256;         // 75000
  const int gemmGrid = (NODES + 127) / 128;              // 313

  const float* cur = x;
  for (int l = 0; l < 3; ++l) {
    const int base = 2 + l * 8;  // c{l}_w1,b1,g,bt,mu,var,w2,b2
    init_copy<<<initGrid, blk, 0, stream>>>((const float4*)cur, (float4*)b0, n4);
    edge_scatter<<<scatGrid, blk, 0, stream>>>(cur, ei, b0);
    gemm_fused<128, 1><<<gemmGrid, blk, 0, stream>>>(
        b0, p[base + 0], p[base + 1], p[base + 2], p[base + 3], p[base + 4],
        p[base + 5], b1);
    gemm_fused<128, 2><<<gemmGrid, blk, 0, stream>>>(
        b1, p[base + 6], p[base + 7], nullptr, nullptr, nullptr, nullptr, b2);
    cur = b2;
  }
  // head: lin1 (ELU) then lin2 (plain) -> d_out
  gemm_fused<128, 2><<<gemmGrid, blk, 0, stream>>>(
      b2, p[26], p[27], nullptr, nullptr, nullptr, nullptr, b1);
  gemm_fused<64, 3><<<gemmGrid, blk, 0, stream>>>(
      b1, p[28], p[29], nullptr, nullptr, nullptr, nullptr, (float*)d_out);
}

// Round 2
// 662.378 us; speedup vs baseline: 5.2519x; 5.2519x over previous
//
#include <hip/hip_runtime.h>
#include <cmath>

#define NODES 40000
#define EDGES 600000
#define HD    128
#define BN_EPS 1e-5f

// ---------------- CSR build ----------------

__global__ __launch_bounds__(256) void zero_i(int* __restrict__ p, int n) {
  int i = blockIdx.x * 256 + threadIdx.x;
  if (i < n) p[i] = 0;
}

__global__ __launch_bounds__(256) void hist_dst(const int* __restrict__ ei,
                                                int* __restrict__ deg) {
  int e = blockIdx.x * 256 + threadIdx.x;
  if (e < EDGES) atomicAdd(&deg[ei[EDGES + e]], 1);
}

// exclusive scan of deg[NODES] -> off[NODES+1]; single block of 1024.
__global__ __launch_bounds__(1024) void exscan(const int* __restrict__ deg,
                                               int* __restrict__ off) {
  __shared__ int wsum[16];
  __shared__ int carry_s;
  const int tid = threadIdx.x;
  const int lane = tid & 63, wv = tid >> 6;
  if (tid == 0) carry_s = 0;
  __syncthreads();
  for (int base = 0; base < NODES; base += 1024) {
    int i = base + tid;
    int v = (i < NODES) ? deg[i] : 0;
    int s = v;  // inclusive wave scan
#pragma unroll
    for (int d = 1; d < 64; d <<= 1) {
      int t = __shfl_up(s, d, 64);
      if (lane >= d) s += t;
    }
    if (lane == 63) wsum[wv] = s;
    __syncthreads();
    if (wv == 0) {
      int ws = (lane < 16) ? wsum[lane] : 0;
#pragma unroll
      for (int d = 1; d < 16; d <<= 1) {
        int t = __shfl_up(ws, d, 64);
        if (lane >= d) ws += t;
      }
      if (lane < 16) wsum[lane] = ws;  // inclusive over waves
    }
    __syncthreads();
    int carry = carry_s;
    int excl = carry + (wv > 0 ? wsum[wv - 1] : 0) + s - v;
    if (i < NODES) off[i] = excl;
    __syncthreads();
    if (tid == 1023) carry_s = carry + wsum[15];
    __syncthreads();
  }
  if (tid == 0) off[NODES] = carry_s;
}

__global__ __launch_bounds__(256) void copy_i(const int* __restrict__ a,
                                              int* __restrict__ b, int n) {
  int i = blockIdx.x * 256 + threadIdx.x;
  if (i < n) b[i] = a[i];
}

__global__ __launch_bounds__(256) void fill_csr(const int* __restrict__ ei,
                                                int* __restrict__ cursor,
                                                int* __restrict__ slot) {
  int e = blockIdx.x * 256 + threadIdx.x;
  if (e >= EDGES) return;
  int s = ei[e];
  int d = ei[EDGES + e];
  int pos = atomicAdd(&cursor[d], 1);
  slot[pos] = s;
}

// ---------------- aggregation: agg[i] = x[i] + sum_{e: dst==i} x[src[e]] ----
// one wave per node; lane handles float2 -> 128 floats/row.
__global__ __launch_bounds__(256) void gather_agg(const float* __restrict__ x,
                                                  const int* __restrict__ off,
                                                  const int* __restrict__ slot,
                                                  float* __restrict__ agg) {
  int node = blockIdx.x * 4 + (threadIdx.x >> 6);
  int lane = threadIdx.x & 63;
  if (node >= NODES) return;
  float2 acc = ((const float2*)(x + (size_t)node * HD))[lane];  // self term
  int i = off[node], e1 = off[node + 1];
  for (; i + 1 < e1; i += 2) {
    int sa = slot[i], sb = slot[i + 1];
    float2 va = ((const float2*)(x + (size_t)sa * HD))[lane];
    float2 vb = ((const float2*)(x + (size_t)sb * HD))[lane];
    acc.x += va.x + vb.x;
    acc.y += va.y + vb.y;
  }
  if (i < e1) {
    int sa = slot[i];
    float2 va = ((const float2*)(x + (size_t)sa * HD))[lane];
    acc.x += va.x;
    acc.y += va.y;
  }
  ((float2*)(agg + (size_t)node * HD))[lane] = acc;
}

// ---------------- fused GEMM + BN/ELU epilogue ----------------
// out[M x NC] = epilogue(A[M x 128] @ W[128 x NC] + bias)
// EPI: 1 = BatchNorm+ELU, 2 = ELU, 3 = none
template <int NC, int EPI>
__global__ __launch_bounds__(256) void gemm_fused(
    const float* __restrict__ A, const float* __restrict__ W,
    const float* __restrict__ bias, const float* __restrict__ g,
    const float* __restrict__ bt, const float* __restrict__ mu,
    const float* __restrict__ var, float* __restrict__ out) {
  constexpr int BM = 128, BK = 32, TM = 8, TN = NC / 16;
  __shared__ float Ast[BK][BM + 4];
  __shared__ float Ws[BK][NC + 4];

  const int tid = threadIdx.x;
  const int tx = tid & 15;
  const int ty = tid >> 4;
  const int m0 = blockIdx.x * BM;

  float acc[TM][TN];
#pragma unroll
  for (int i = 0; i < TM; ++i)
#pragma unroll
    for (int j = 0; j < TN; ++j) acc[i][j] = 0.f;

  for (int k0 = 0; k0 < HD; k0 += BK) {
#pragma unroll
    for (int it = 0; it < 4; ++it) {
      int t = tid + it * 256;
      int r = t >> 3;
      int cc = t & 7;
      int m = m0 + r;
      float4 v = make_float4(0.f, 0.f, 0.f, 0.f);
      if (m < NODES) v = *(const float4*)(A + (size_t)m * HD + k0 + cc * 4);
      Ast[cc * 4 + 0][r] = v.x;
      Ast[cc * 4 + 1][r] = v.y;
      Ast[cc * 4 + 2][r] = v.z;
      Ast[cc * 4 + 3][r] = v.w;
    }
    constexpr int F4 = NC / 4;
#pragma unroll
    for (int t = tid; t < BK * F4; t += 256) {
      int r = t / F4;
      int cc = t % F4;
      *(float4*)&Ws[r][cc * 4] = *(const float4*)(W + (size_t)(k0 + r) * NC + cc * 4);
    }
    __syncthreads();

#pragma unroll
    for (int k = 0; k < BK; ++k) {
      float a[TM], w[TN];
      *(float4*)&a[0] = *(const float4*)&Ast[k][ty * TM + 0];
      *(float4*)&a[4] = *(const float4*)&Ast[k][ty * TM + 4];
#pragma unroll
      for (int j4 = 0; j4 < TN; j4 += 4)
        *(float4*)&w[j4] = *(const float4*)&Ws[k][tx * TN + j4];
#pragma unroll
      for (int i = 0; i < TM; ++i)
#pragma unroll
        for (int j = 0; j < TN; ++j)
          acc[i][j] = fmaf(a[i], w[j], acc[i][j]);
    }
    __syncthreads();
  }

#pragma unroll
  for (int i = 0; i < TM; ++i) {
    int m = m0 + ty * TM + i;
    if (m >= NODES) break;
#pragma unroll
    for (int j = 0; j < TN; ++j) {
      int c = tx * TN + j;
      float t = acc[i][j] + bias[c];
      if (EPI == 1) {
        float rs = rsqrtf(var[c] + BN_EPS);
        t = (t - mu[c]) * rs * g[c] + bt[c];
      }
      if (EPI <= 2) t = t > 0.f ? t : expm1f(t);
      acc[i][j] = t;
    }
#pragma unroll
    for (int j4 = 0; j4 < TN; j4 += 4)
      *(float4*)(out + (size_t)m * NC + tx * TN + j4) = *(float4*)&acc[i][j4];
  }
}

extern "C" void kernel_launch(void* const* d_in, const int* in_sizes, int n_in,
                              void* d_out, int out_size, void* d_ws, size_t ws_size,
                              hipStream_t stream) {
  const float* x = (const float*)d_in[0];
  const int* ei  = (const int*)d_in[1];
  const float* p[30];
  for (int i = 0; i < 30 && i < n_in; ++i) p[i] = (const float*)d_in[i];

  // workspace layout: 2 node-feature buffers + CSR (off, cursor, slot)
  float* bufA = (float*)d_ws;
  float* bufB = bufA + (size_t)NODES * HD;
  int* off    = (int*)(bufB + (size_t)NODES * HD);
  int* cursor = off + (NODES + 1);
  int* slot   = cursor + NODES;

  dim3 blk(256);
  const int nodeGrid  = (NODES + 255) / 256;     // 157
  const int edgeGrid  = (EDGES + 255) / 256;     // 2344
  const int gathGrid  = (NODES + 3) / 4;         // 10000
  const int gemmGrid  = (NODES + 127) / 128;     // 313

  // --- build CSR (by dst) once; reused by all 3 layers ---
  zero_i<<<nodeGrid, blk, 0, stream>>>(cursor, NODES);          // cursor = deg
  hist_dst<<<edgeGrid, blk, 0, stream>>>(ei, cursor);
  exscan<<<1, 1024, 0, stream>>>(cursor, off);
  copy_i<<<nodeGrid, blk, 0, stream>>>(off, cursor, NODES);
  fill_csr<<<edgeGrid, blk, 0, stream>>>(ei, cursor, slot);

  // --- 3 GIN layers, ping-pong bufA/bufB ---
  const float* cur = x;
  for (int l = 0; l < 3; ++l) {
    const int base = 2 + l * 8;  // c{l}_w1,b1,g,bt,mu,var,w2,b2
    gather_agg<<<gathGrid, blk, 0, stream>>>(cur, off, slot, bufA);
    gemm_fused<128, 1><<<gemmGrid, blk, 0, stream>>>(
        bufA, p[base + 0], p[base + 1], p[base + 2], p[base + 3], p[base + 4],
        p[base + 5], bufB);
    gemm_fused<128, 2><<<gemmGrid, blk, 0, stream>>>(
        bufB, p[base + 6], p[base + 7], nullptr, nullptr, nullptr, nullptr,
        bufA);
    cur = bufA;
    float* t = bufA; bufA = bufB; bufB = t;
  }

  // --- head: lin1 (ELU) then lin2 (plain) -> d_out ---
  gemm_fused<128, 2><<<gemmGrid, blk, 0, stream>>>(
      cur, p[26], p[27], nullptr, nullptr, nullptr, nullptr, bufA);
  gemm_fused<64, 3><<<gemmGrid, blk, 0, stream>>>(
      bufA, p[28], p[29], nullptr, nullptr, nullptr, nullptr, (float*)d_out);
}